// Round 1
// baseline (568.914 us; speedup 1.0000x reference)
//
#include <hip/hip_runtime.h>
#include <math.h>

#define N_NODES 100000
#define N_EDGES 1600000
#define N_GRAPHS 64

// ---------------- degree count ----------------
__global__ __launch_bounds__(256) void deg_kernel(const int* __restrict__ dst, int* __restrict__ cnt) {
    int e = blockIdx.x * 256 + threadIdx.x;
    if (e < N_EDGES) atomicAdd(&cnt[dst[e]], 1);
}

// ---------------- dis + row allocation (wave scan, one atomic per wave) ----------------
__global__ __launch_bounds__(256) void alloc_kernel(const int* __restrict__ cnt, float* __restrict__ dis,
                                                    int* __restrict__ rowptr, int* __restrict__ total) {
    int i = blockIdx.x * 256 + threadIdx.x;
    int c = (i < N_NODES) ? cnt[i] : 0;
    if (i < N_NODES) dis[i] = rsqrtf((float)(c + 1));
    int lane = threadIdx.x & 63;
    int s = c;
    #pragma unroll
    for (int o = 1; o < 64; o <<= 1) {
        int v = __shfl_up(s, o, 64);
        if (lane >= o) s += v;
    }
    int wtot = __shfl(s, 63, 64);
    int base = 0;
    if (lane == 0) base = atomicAdd(total, wtot);
    base = __shfl(base, 0, 64);
    if (i < N_NODES) rowptr[i] = base + s - c;   // exclusive within wave
}

// ---------------- CSR fill ----------------
__global__ __launch_bounds__(256) void fill_kernel(const int* __restrict__ src, const int* __restrict__ dst,
                                                   const int* __restrict__ rowptr, int* __restrict__ cursor,
                                                   int* __restrict__ colb) {
    int e = blockIdx.x * 256 + threadIdx.x;
    if (e >= N_EDGES) return;
    int d = dst[e];
    int p = atomicAdd(&cursor[d], 1);
    colb[rowptr[d] + p] = src[e];
}

// ---------------- GEMM1: hs1 = dis * (x @ W1), [N,128]x[128,32] ----------------
__global__ __launch_bounds__(256) void gemm1_kernel(const float* __restrict__ x, const float* __restrict__ W1,
                                                    const float* __restrict__ dis, float* __restrict__ hs1) {
    __shared__ float xs[64][128];     // 32 KB
    __shared__ float wt[32][132];     // W1^T padded (132*4=528=33*16 keeps float4 aligned)
    int tid = threadIdx.x;
    int r0 = blockIdx.x * 64;
    for (int idx = tid; idx < 128 * 32; idx += 256) {
        int k = idx >> 5, j = idx & 31;
        wt[j][k] = W1[idx];
    }
    for (int idx = tid; idx < 64 * 32; idx += 256) {   // float4 chunks of x rows
        int r = idx >> 5, kc = idx & 31;
        int gr = r0 + r;
        float4 v = (gr < N_NODES) ? ((const float4*)x)[(size_t)gr * 32 + kc] : make_float4(0.f, 0.f, 0.f, 0.f);
        *(float4*)&xs[r][kc * 4] = v;
    }
    __syncthreads();
    int j = tid & 31;
    int rr = tid >> 5;   // 0..7
    float acc[8];
    #pragma unroll
    for (int i = 0; i < 8; i++) acc[i] = 0.f;
    for (int kc = 0; kc < 128; kc += 4) {
        float4 wv = *(const float4*)&wt[j][kc];
        #pragma unroll
        for (int i = 0; i < 8; i++) {
            float4 xv = *(const float4*)&xs[rr + i * 8][kc];
            acc[i] += xv.x * wv.x + xv.y * wv.y + xv.z * wv.z + xv.w * wv.w;
        }
    }
    #pragma unroll
    for (int i = 0; i < 8; i++) {
        int gr = r0 + rr + i * 8;
        if (gr < N_NODES) hs1[(size_t)gr * 32 + j] = dis[gr] * acc[i];
    }
}

// ---------------- agg layer1: h1 = lrelu(dis*(sum_neigh hs1 + hs1_self) + b1) ----------------
__global__ __launch_bounds__(256) void agg1_kernel(const float* __restrict__ hs1, const int* __restrict__ colb,
                                                   const int* __restrict__ rowptr, const int* __restrict__ cnt,
                                                   const float* __restrict__ dis, const float* __restrict__ b1,
                                                   float* __restrict__ h1) {
    int tid = threadIdx.x;
    int f = tid & 31;
    int r = blockIdx.x * 8 + (tid >> 5);
    if (r >= N_NODES) return;
    int start = rowptr[r];
    int n = cnt[r];
    float s0 = hs1[(size_t)r * 32 + f], s1 = 0.f, s2 = 0.f, s3 = 0.f;
    int k = 0;
    for (; k + 4 <= n; k += 4) {
        int c0 = colb[start + k + 0];
        int c1 = colb[start + k + 1];
        int c2 = colb[start + k + 2];
        int c3 = colb[start + k + 3];
        s0 += hs1[(size_t)c0 * 32 + f];
        s1 += hs1[(size_t)c1 * 32 + f];
        s2 += hs1[(size_t)c2 * 32 + f];
        s3 += hs1[(size_t)c3 * 32 + f];
    }
    for (; k < n; k++) s0 += hs1[(size_t)colb[start + k] * 32 + f];
    float v = dis[r] * ((s0 + s1) + (s2 + s3)) + b1[f];
    h1[(size_t)r * 32 + f] = v > 0.f ? v : 0.1f * v;
}

// ---------------- GEMM2: hs2 = dis * (h1 @ W2), [N,32]x[32,64] ----------------
__global__ __launch_bounds__(256) void gemm2_kernel(const float* __restrict__ h1, const float* __restrict__ W2,
                                                    const float* __restrict__ dis, float* __restrict__ hs2) {
    __shared__ float hsd[64][32];    // 8 KB
    __shared__ float wt[64][36];     // W2^T padded (36*4=144=9*16 aligned)
    int tid = threadIdx.x;
    int r0 = blockIdx.x * 64;
    for (int idx = tid; idx < 32 * 64; idx += 256) {
        int k = idx >> 6, j = idx & 63;
        wt[j][k] = W2[idx];
    }
    for (int idx = tid; idx < 64 * 8; idx += 256) {
        int r = idx >> 3, kc = idx & 7;
        int gr = r0 + r;
        float4 v = (gr < N_NODES) ? ((const float4*)h1)[(size_t)gr * 8 + kc] : make_float4(0.f, 0.f, 0.f, 0.f);
        *(float4*)&hsd[r][kc * 4] = v;
    }
    __syncthreads();
    int j = tid & 63;
    int rr = tid >> 6;   // wave id 0..3
    float acc[16];
    #pragma unroll
    for (int i = 0; i < 16; i++) acc[i] = 0.f;
    for (int kc = 0; kc < 32; kc += 4) {
        float4 wv = *(const float4*)&wt[j][kc];
        #pragma unroll
        for (int i = 0; i < 16; i++) {
            float4 xv = *(const float4*)&hsd[rr + i * 4][kc];
            acc[i] += xv.x * wv.x + xv.y * wv.y + xv.z * wv.z + xv.w * wv.w;
        }
    }
    #pragma unroll
    for (int i = 0; i < 16; i++) {
        int gr = r0 + rr + i * 4;
        if (gr < N_NODES) hs2[(size_t)gr * 64 + j] = dis[gr] * acc[i];
    }
}

// ---------------- agg layer2 (no lrelu) ----------------
__global__ __launch_bounds__(256) void agg2_kernel(const float* __restrict__ hs2, const int* __restrict__ colb,
                                                   const int* __restrict__ rowptr, const int* __restrict__ cnt,
                                                   const float* __restrict__ dis, const float* __restrict__ b2,
                                                   float* __restrict__ h2) {
    int tid = threadIdx.x;
    int f = tid & 63;
    int r = blockIdx.x * 4 + (tid >> 6);
    if (r >= N_NODES) return;
    int start = rowptr[r];
    int n = cnt[r];
    float s0 = hs2[(size_t)r * 64 + f], s1 = 0.f, s2 = 0.f, s3 = 0.f;
    int k = 0;
    for (; k + 4 <= n; k += 4) {
        int c0 = colb[start + k + 0];
        int c1 = colb[start + k + 1];
        int c2 = colb[start + k + 2];
        int c3 = colb[start + k + 3];
        s0 += hs2[(size_t)c0 * 64 + f];
        s1 += hs2[(size_t)c1 * 64 + f];
        s2 += hs2[(size_t)c2 * 64 + f];
        s3 += hs2[(size_t)c3 * 64 + f];
    }
    for (; k < n; k++) s0 += hs2[(size_t)colb[start + k] * 64 + f];
    h2[(size_t)r * 64 + f] = dis[r] * ((s0 + s1) + (s2 + s3)) + b2[f];
}

// ---------------- graph boundaries from sorted batch ----------------
__global__ __launch_bounds__(256) void goff_kernel(const int* __restrict__ batch, int* __restrict__ goff) {
    int i = blockIdx.x * 256 + threadIdx.x;
    if (i >= N_NODES) return;
    int b = batch[i];
    if (i == 0) {
        for (int g = 0; g <= b; g++) goff[g] = 0;
    }
    int bn = (i + 1 < N_NODES) ? batch[i + 1] : N_GRAPHS;
    for (int g = b + 1; g <= bn; g++) goff[g] = i + 1;
}

// ---------------- global max pool: one block per graph ----------------
__global__ __launch_bounds__(256) void pool_kernel(const float* __restrict__ h2, const int* __restrict__ goff,
                                                   float* __restrict__ gbuf) {
    __shared__ float red[4][64];
    int g = blockIdx.x;
    int f = threadIdx.x & 63;
    int q = threadIdx.x >> 6;
    int lo = goff[g], hi = goff[g + 1];
    float m = -INFINITY;
    for (int r = lo + q; r < hi; r += 4) m = fmaxf(m, h2[(size_t)r * 64 + f]);
    red[q][f] = m;
    __syncthreads();
    if (q == 0) gbuf[g * 64 + f] = fmaxf(fmaxf(red[0][f], red[1][f]), fmaxf(red[2][f], red[3][f]));
}

// ---------------- MLP head, single block ----------------
__global__ __launch_bounds__(256) void mlp_kernel(const float* __restrict__ gbuf,
                                                  const float* __restrict__ Wl1, const float* __restrict__ bl1,
                                                  const float* __restrict__ Wl2, const float* __restrict__ bl2,
                                                  const float* __restrict__ Wl3, const float* __restrict__ bl3,
                                                  float* __restrict__ out) {
    __shared__ float A[64][64];    // g, then reused for g2
    __shared__ float B[64][128];   // g1
    int tid = threadIdx.x;
    for (int idx = tid; idx < 64 * 64; idx += 256) A[idx >> 6][idx & 63] = gbuf[idx];
    __syncthreads();
    // g1 = lrelu(A @ Wl1 + bl1), Wl1 [64][128]
    {
        int j = tid & 127;
        int rg = tid >> 7;   // 0..1
        float wc[64];
        #pragma unroll
        for (int k = 0; k < 64; k++) wc[k] = Wl1[k * 128 + j];
        float bj = bl1[j];
        for (int r = rg; r < 64; r += 2) {
            float acc = bj;
            #pragma unroll
            for (int kc = 0; kc < 64; kc += 4) {
                float4 av = *(const float4*)&A[r][kc];
                acc += av.x * wc[kc] + av.y * wc[kc + 1] + av.z * wc[kc + 2] + av.w * wc[kc + 3];
            }
            B[r][j] = acc > 0.f ? acc : 0.1f * acc;
        }
    }
    __syncthreads();
    // g2 = lrelu(B @ Wl2 + bl2), Wl2 [128][64] -> overwrite A
    {
        int j = tid & 63;
        int rg = tid >> 6;   // 0..3
        float wc[128];
        #pragma unroll
        for (int k = 0; k < 128; k++) wc[k] = Wl2[k * 64 + j];
        float bj = bl2[j];
        for (int r = rg; r < 64; r += 4) {
            float acc = bj;
            #pragma unroll
            for (int kc = 0; kc < 128; kc += 4) {
                float4 bv = *(const float4*)&B[r][kc];
                acc += bv.x * wc[kc] + bv.y * wc[kc + 1] + bv.z * wc[kc + 2] + bv.w * wc[kc + 3];
            }
            A[r][j] = acc > 0.f ? acc : 0.1f * acc;
        }
    }
    __syncthreads();
    // out = A @ Wl3 + bl3, Wl3 [64][1]
    if (tid < 64) {
        int r = tid;
        float acc = bl3[0];
        #pragma unroll
        for (int k = 0; k < 64; k++) acc += A[r][k] * Wl3[k];
        out[r] = acc;
    }
}

extern "C" void kernel_launch(void* const* d_in, const int* in_sizes, int n_in,
                              void* d_out, int out_size, void* d_ws, size_t ws_size,
                              hipStream_t stream) {
    (void)in_sizes; (void)n_in; (void)out_size; (void)ws_size;
    const float* x    = (const float*)d_in[0];
    const int*   edge = (const int*)d_in[1];
    const int*   batch= (const int*)d_in[2];
    const float* W1   = (const float*)d_in[3];
    const float* b1   = (const float*)d_in[4];
    const float* W2   = (const float*)d_in[5];
    const float* b2   = (const float*)d_in[6];
    const float* Wl1  = (const float*)d_in[7];
    const float* bl1  = (const float*)d_in[8];
    const float* Wl2  = (const float*)d_in[9];
    const float* bl2  = (const float*)d_in[10];
    const float* Wl3  = (const float*)d_in[11];
    const float* bl3  = (const float*)d_in[12];
    const int* srcp = edge;
    const int* dstp = edge + N_EDGES;

    // workspace layout
    char* ws = (char*)d_ws;
    // zeroed region: cnt[N], cursor[N], total[1] contiguous -> one memset
    int* cnt    = (int*)ws;
    int* cursor = cnt + N_NODES;
    int* total  = cursor + N_NODES;
    size_t off = (((size_t)(2 * N_NODES + 1) * 4) + 255) & ~(size_t)255;
    auto alloc = [&](size_t bytes) { char* p = ws + off; off = (off + bytes + 255) & ~(size_t)255; return p; };
    int*   rowptr = (int*)alloc((size_t)N_NODES * 4);
    float* dis    = (float*)alloc((size_t)N_NODES * 4);
    int*   colb   = (int*)alloc((size_t)N_EDGES * 4);
    float* hs1    = (float*)alloc((size_t)N_NODES * 32 * 4);
    float* h1     = (float*)alloc((size_t)N_NODES * 32 * 4);
    float* hs2    = (float*)alloc((size_t)N_NODES * 64 * 4);
    float* h2     = (float*)alloc((size_t)N_NODES * 64 * 4);
    int*   goff   = (int*)alloc(65 * 4);
    float* gbuf   = (float*)alloc(64 * 64 * 4);

    hipMemsetAsync(ws, 0, (size_t)(2 * N_NODES + 1) * sizeof(int), stream);

    deg_kernel  <<<(N_EDGES + 255) / 256, 256, 0, stream>>>(dstp, cnt);
    alloc_kernel<<<(N_NODES + 255) / 256, 256, 0, stream>>>(cnt, dis, rowptr, total);
    fill_kernel <<<(N_EDGES + 255) / 256, 256, 0, stream>>>(srcp, dstp, rowptr, cursor, colb);
    gemm1_kernel<<<(N_NODES + 63) / 64, 256, 0, stream>>>(x, W1, dis, hs1);
    agg1_kernel <<<(N_NODES + 7) / 8, 256, 0, stream>>>(hs1, colb, rowptr, cnt, dis, b1, h1);
    gemm2_kernel<<<(N_NODES + 63) / 64, 256, 0, stream>>>(h1, W2, dis, hs2);
    agg2_kernel <<<(N_NODES + 3) / 4, 256, 0, stream>>>(hs2, colb, rowptr, cnt, dis, b2, h2);
    goff_kernel <<<(N_NODES + 255) / 256, 256, 0, stream>>>(batch, goff);
    pool_kernel <<<N_GRAPHS, 256, 0, stream>>>(h2, goff, gbuf);
    mlp_kernel  <<<1, 256, 0, stream>>>(gbuf, Wl1, bl1, Wl2, bl2, Wl3, bl3, (float*)d_out);
}

// Round 2
// 490.291 us; speedup vs baseline: 1.1604x; 1.1604x over previous
//
#include <hip/hip_runtime.h>
#include <math.h>

#define N_NODES 100000
#define N_EDGES 1600000
#define N_GRAPHS 64

// ---------------- degree count + per-edge slot ----------------
__global__ __launch_bounds__(256) void deg_kernel(const int* __restrict__ dst, int* __restrict__ cnt,
                                                  int* __restrict__ pos) {
    int e = blockIdx.x * 256 + threadIdx.x;
    if (e < N_EDGES) pos[e] = atomicAdd(&cnt[dst[e]], 1);
}

// ---------------- dis + row allocation (wave scan) + graph offsets ----------------
__global__ __launch_bounds__(256) void alloc_kernel(const int* __restrict__ cnt, const int* __restrict__ batch,
                                                    float* __restrict__ dis, int* __restrict__ rowptr,
                                                    int* __restrict__ total, int* __restrict__ goff) {
    int i = blockIdx.x * 256 + threadIdx.x;
    int c = (i < N_NODES) ? cnt[i] : 0;
    if (i < N_NODES) dis[i] = rsqrtf((float)(c + 1));
    int lane = threadIdx.x & 63;
    int s = c;
    #pragma unroll
    for (int o = 1; o < 64; o <<= 1) {
        int v = __shfl_up(s, o, 64);
        if (lane >= o) s += v;
    }
    int wtot = __shfl(s, 63, 64);
    int base = 0;
    if (lane == 0) base = atomicAdd(total, wtot);
    base = __shfl(base, 0, 64);
    if (i < N_NODES) rowptr[i] = base + s - c;   // exclusive within wave
    // graph boundaries from sorted batch
    if (i < N_NODES) {
        int b = batch[i];
        if (i == 0) {
            for (int g = 0; g <= b; g++) goff[g] = 0;
        }
        int bn = (i + 1 < N_NODES) ? batch[i + 1] : N_GRAPHS;
        for (int g = b + 1; g <= bn; g++) goff[g] = i + 1;
    }
}

// ---------------- CSR fill (no atomics: slot precomputed) ----------------
__global__ __launch_bounds__(256) void fill_kernel(const int* __restrict__ src, const int* __restrict__ dst,
                                                   const int* __restrict__ rowptr, const int* __restrict__ pos,
                                                   int* __restrict__ colb) {
    int e = blockIdx.x * 256 + threadIdx.x;
    if (e >= N_EDGES) return;
    colb[rowptr[dst[e]] + pos[e]] = src[e];
}

// ---------------- GEMM1: hs1 = dis * (x @ W1), [N,128]x[128,32] ----------------
__global__ __launch_bounds__(256) void gemm1_kernel(const float* __restrict__ x, const float* __restrict__ W1,
                                                    const float* __restrict__ dis, float* __restrict__ hs1) {
    __shared__ float xs[64][128];     // 32 KB
    __shared__ float wt[32][132];     // W1^T padded
    int tid = threadIdx.x;
    int r0 = blockIdx.x * 64;
    for (int idx = tid; idx < 128 * 32; idx += 256) {
        int k = idx >> 5, j = idx & 31;
        wt[j][k] = W1[idx];
    }
    for (int idx = tid; idx < 64 * 32; idx += 256) {
        int r = idx >> 5, kc = idx & 31;
        int gr = r0 + r;
        float4 v = (gr < N_NODES) ? ((const float4*)x)[(size_t)gr * 32 + kc] : make_float4(0.f, 0.f, 0.f, 0.f);
        *(float4*)&xs[r][kc * 4] = v;
    }
    __syncthreads();
    int j = tid & 31;
    int rr = tid >> 5;   // 0..7
    float acc[8];
    #pragma unroll
    for (int i = 0; i < 8; i++) acc[i] = 0.f;
    for (int kc = 0; kc < 128; kc += 4) {
        float4 wv = *(const float4*)&wt[j][kc];
        #pragma unroll
        for (int i = 0; i < 8; i++) {
            float4 xv = *(const float4*)&xs[rr + i * 8][kc];
            acc[i] += xv.x * wv.x + xv.y * wv.y + xv.z * wv.z + xv.w * wv.w;
        }
    }
    #pragma unroll
    for (int i = 0; i < 8; i++) {
        int gr = r0 + rr + i * 8;
        if (gr < N_NODES) hs1[(size_t)gr * 32 + j] = dis[gr] * acc[i];
    }
}

// ---------------- agg1 + gemm2 fused:
//   h1 = lrelu(dis*(sum_neigh hs1 + hs1_self) + b1)   (in LDS, never hits global)
//   hs2 = dis * (h1 @ W2)
__global__ __launch_bounds__(256) void agg1_kernel(const float* __restrict__ hs1, const int* __restrict__ colb,
                                                   const int* __restrict__ rowptr, const int* __restrict__ cnt,
                                                   const float* __restrict__ dis, const float* __restrict__ b1,
                                                   const float* __restrict__ W2, float* __restrict__ hs2) {
    __shared__ float h1s[8][33];     // padded
    __shared__ float w2s[32][64];    // W2 as-is; 64-lane row read = 2-way bank alias (free)
    int tid = threadIdx.x;
    for (int idx = tid; idx < 32 * 64; idx += 256) w2s[idx >> 6][idx & 63] = W2[idx];
    int f = tid & 31;
    int rl = tid >> 5;               // 0..7
    int r = blockIdx.x * 8 + rl;
    if (r < N_NODES) {
        int start = rowptr[r];
        int n = cnt[r];
        float s0 = hs1[(size_t)r * 32 + f], s1 = 0.f, s2 = 0.f, s3 = 0.f;
        float s4 = 0.f, s5 = 0.f, s6 = 0.f, s7 = 0.f;
        int k = 0;
        for (; k + 8 <= n; k += 8) {
            int c0 = colb[start + k + 0];
            int c1 = colb[start + k + 1];
            int c2 = colb[start + k + 2];
            int c3 = colb[start + k + 3];
            int c4 = colb[start + k + 4];
            int c5 = colb[start + k + 5];
            int c6 = colb[start + k + 6];
            int c7 = colb[start + k + 7];
            s0 += hs1[(size_t)c0 * 32 + f];
            s1 += hs1[(size_t)c1 * 32 + f];
            s2 += hs1[(size_t)c2 * 32 + f];
            s3 += hs1[(size_t)c3 * 32 + f];
            s4 += hs1[(size_t)c4 * 32 + f];
            s5 += hs1[(size_t)c5 * 32 + f];
            s6 += hs1[(size_t)c6 * 32 + f];
            s7 += hs1[(size_t)c7 * 32 + f];
        }
        for (; k < n; k++) s0 += hs1[(size_t)colb[start + k] * 32 + f];
        float v = dis[r] * (((s0 + s1) + (s2 + s3)) + ((s4 + s5) + (s6 + s7))) + b1[f];
        h1s[rl][f] = v > 0.f ? v : 0.1f * v;
    }
    __syncthreads();
    // phase 2: hs2[r] = dis[r] * (h1[r] @ W2)  — 2 rows per thread-quarter
    int j = tid & 63;
    int rq = tid >> 6;               // 0..3
    int g0 = blockIdx.x * 8 + rq;
    int g1 = g0 + 4;
    float a0 = 0.f, a1 = 0.f;
    #pragma unroll
    for (int k2 = 0; k2 < 32; k2++) {
        float wv = w2s[k2][j];
        a0 += h1s[rq][k2] * wv;       // broadcast read
        a1 += h1s[rq + 4][k2] * wv;
    }
    if (g0 < N_NODES) hs2[(size_t)g0 * 64 + j] = dis[g0] * a0;
    if (g1 < N_NODES) hs2[(size_t)g1 * 64 + j] = dis[g1] * a1;
}

// ---------------- agg layer2 (no lrelu) ----------------
__global__ __launch_bounds__(256) void agg2_kernel(const float* __restrict__ hs2, const int* __restrict__ colb,
                                                   const int* __restrict__ rowptr, const int* __restrict__ cnt,
                                                   const float* __restrict__ dis, const float* __restrict__ b2,
                                                   float* __restrict__ h2) {
    int tid = threadIdx.x;
    int f = tid & 63;
    int r = blockIdx.x * 4 + (tid >> 6);
    if (r >= N_NODES) return;
    int start = rowptr[r];
    int n = cnt[r];
    float s0 = hs2[(size_t)r * 64 + f], s1 = 0.f, s2 = 0.f, s3 = 0.f;
    float s4 = 0.f, s5 = 0.f, s6 = 0.f, s7 = 0.f;
    int k = 0;
    for (; k + 8 <= n; k += 8) {
        int c0 = colb[start + k + 0];
        int c1 = colb[start + k + 1];
        int c2 = colb[start + k + 2];
        int c3 = colb[start + k + 3];
        int c4 = colb[start + k + 4];
        int c5 = colb[start + k + 5];
        int c6 = colb[start + k + 6];
        int c7 = colb[start + k + 7];
        s0 += hs2[(size_t)c0 * 64 + f];
        s1 += hs2[(size_t)c1 * 64 + f];
        s2 += hs2[(size_t)c2 * 64 + f];
        s3 += hs2[(size_t)c3 * 64 + f];
        s4 += hs2[(size_t)c4 * 64 + f];
        s5 += hs2[(size_t)c5 * 64 + f];
        s6 += hs2[(size_t)c6 * 64 + f];
        s7 += hs2[(size_t)c7 * 64 + f];
    }
    for (; k < n; k++) s0 += hs2[(size_t)colb[start + k] * 64 + f];
    h2[(size_t)r * 64 + f] = dis[r] * (((s0 + s1) + (s2 + s3)) + ((s4 + s5) + (s6 + s7))) + b2[f];
}

// ---------------- global max pool: one block per graph ----------------
__global__ __launch_bounds__(256) void pool_kernel(const float* __restrict__ h2, const int* __restrict__ goff,
                                                   float* __restrict__ gbuf) {
    __shared__ float red[4][64];
    int g = blockIdx.x;
    int f = threadIdx.x & 63;
    int q = threadIdx.x >> 6;
    int lo = goff[g], hi = goff[g + 1];
    float m = -INFINITY;
    for (int r = lo + q; r < hi; r += 4) m = fmaxf(m, h2[(size_t)r * 64 + f]);
    red[q][f] = m;
    __syncthreads();
    if (q == 0) gbuf[g * 64 + f] = fmaxf(fmaxf(red[0][f], red[1][f]), fmaxf(red[2][f], red[3][f]));
}

// ---------------- MLP head, single block ----------------
__global__ __launch_bounds__(256) void mlp_kernel(const float* __restrict__ gbuf,
                                                  const float* __restrict__ Wl1, const float* __restrict__ bl1,
                                                  const float* __restrict__ Wl2, const float* __restrict__ bl2,
                                                  const float* __restrict__ Wl3, const float* __restrict__ bl3,
                                                  float* __restrict__ out) {
    __shared__ float A[64][64];
    __shared__ float B[64][128];
    int tid = threadIdx.x;
    for (int idx = tid; idx < 64 * 64; idx += 256) A[idx >> 6][idx & 63] = gbuf[idx];
    __syncthreads();
    {
        int j = tid & 127;
        int rg = tid >> 7;
        float wc[64];
        #pragma unroll
        for (int k = 0; k < 64; k++) wc[k] = Wl1[k * 128 + j];
        float bj = bl1[j];
        for (int r = rg; r < 64; r += 2) {
            float acc = bj;
            #pragma unroll
            for (int kc = 0; kc < 64; kc += 4) {
                float4 av = *(const float4*)&A[r][kc];
                acc += av.x * wc[kc] + av.y * wc[kc + 1] + av.z * wc[kc + 2] + av.w * wc[kc + 3];
            }
            B[r][j] = acc > 0.f ? acc : 0.1f * acc;
        }
    }
    __syncthreads();
    {
        int j = tid & 63;
        int rg = tid >> 6;
        float wc[128];
        #pragma unroll
        for (int k = 0; k < 128; k++) wc[k] = Wl2[k * 64 + j];
        float bj = bl2[j];
        for (int r = rg; r < 64; r += 4) {
            float acc = bj;
            #pragma unroll
            for (int kc = 0; kc < 128; kc += 4) {
                float4 bv = *(const float4*)&B[r][kc];
                acc += bv.x * wc[kc] + bv.y * wc[kc + 1] + bv.z * wc[kc + 2] + bv.w * wc[kc + 3];
            }
            A[r][j] = acc > 0.f ? acc : 0.1f * acc;
        }
    }
    __syncthreads();
    if (tid < 64) {
        int r = tid;
        float acc = bl3[0];
        #pragma unroll
        for (int k = 0; k < 64; k++) acc += A[r][k] * Wl3[k];
        out[r] = acc;
    }
}

extern "C" void kernel_launch(void* const* d_in, const int* in_sizes, int n_in,
                              void* d_out, int out_size, void* d_ws, size_t ws_size,
                              hipStream_t stream) {
    (void)in_sizes; (void)n_in; (void)out_size; (void)ws_size;
    const float* x    = (const float*)d_in[0];
    const int*   edge = (const int*)d_in[1];
    const int*   batch= (const int*)d_in[2];
    const float* W1   = (const float*)d_in[3];
    const float* b1   = (const float*)d_in[4];
    const float* W2   = (const float*)d_in[5];
    const float* b2   = (const float*)d_in[6];
    const float* Wl1  = (const float*)d_in[7];
    const float* bl1  = (const float*)d_in[8];
    const float* Wl2  = (const float*)d_in[9];
    const float* bl2  = (const float*)d_in[10];
    const float* Wl3  = (const float*)d_in[11];
    const float* bl3  = (const float*)d_in[12];
    const int* srcp = edge;
    const int* dstp = edge + N_EDGES;

    // workspace layout: zeroed region first = cnt[N] + total[1] -> one memset
    char* ws = (char*)d_ws;
    int* cnt   = (int*)ws;
    int* total = cnt + N_NODES;
    size_t off = (((size_t)(N_NODES + 1) * 4) + 255) & ~(size_t)255;
    auto alloc = [&](size_t bytes) { char* p = ws + off; off = (off + bytes + 255) & ~(size_t)255; return p; };
    int*   pos    = (int*)alloc((size_t)N_EDGES * 4);
    int*   rowptr = (int*)alloc((size_t)N_NODES * 4);
    float* dis    = (float*)alloc((size_t)N_NODES * 4);
    int*   colb   = (int*)alloc((size_t)N_EDGES * 4);
    float* hs1    = (float*)alloc((size_t)N_NODES * 32 * 4);
    float* hs2    = (float*)alloc((size_t)N_NODES * 64 * 4);
    float* h2     = (float*)alloc((size_t)N_NODES * 64 * 4);
    int*   goff   = (int*)alloc(65 * 4);
    float* gbuf   = (float*)alloc(64 * 64 * 4);

    hipMemsetAsync(ws, 0, (size_t)(N_NODES + 1) * sizeof(int), stream);

    deg_kernel  <<<(N_EDGES + 255) / 256, 256, 0, stream>>>(dstp, cnt, pos);
    alloc_kernel<<<(N_NODES + 255) / 256, 256, 0, stream>>>(cnt, batch, dis, rowptr, total, goff);
    fill_kernel <<<(N_EDGES + 255) / 256, 256, 0, stream>>>(srcp, dstp, rowptr, pos, colb);
    gemm1_kernel<<<(N_NODES + 63) / 64, 256, 0, stream>>>(x, W1, dis, hs1);
    agg1_kernel <<<(N_NODES + 7) / 8, 256, 0, stream>>>(hs1, colb, rowptr, cnt, dis, b1, W2, hs2);
    agg2_kernel <<<(N_NODES + 3) / 4, 256, 0, stream>>>(hs2, colb, rowptr, cnt, dis, b2, h2);
    pool_kernel <<<N_GRAPHS, 256, 0, stream>>>(h2, goff, gbuf);
    mlp_kernel  <<<1, 256, 0, stream>>>(gbuf, Wl1, bl1, Wl2, bl2, Wl3, bl3, (float*)d_out);
}

// Round 3
// 445.903 us; speedup vs baseline: 1.2759x; 1.0995x over previous
//
#include <hip/hip_runtime.h>
#include <math.h>

#define N_NODES 100000
#define N_EDGES 1600000
#define N_GRAPHS 64

// ordered-uint encode for float atomicMax (monotone bijection)
__device__ __forceinline__ unsigned f2o(float f) {
    unsigned u = __float_as_uint(f);
    return (u & 0x80000000u) ? ~u : (u | 0x80000000u);
}
__device__ __forceinline__ float o2f(unsigned u) {
    return (u & 0x80000000u) ? __uint_as_float(u & 0x7fffffffu) : __uint_as_float(~u);
}

// ---------------- degree count + per-edge slot ----------------
__global__ __launch_bounds__(256) void deg_kernel(const int* __restrict__ dst, int* __restrict__ cnt,
                                                  int* __restrict__ pos) {
    int e = blockIdx.x * 256 + threadIdx.x;
    if (e < N_EDGES) pos[e] = atomicAdd(&cnt[dst[e]], 1);
}

// ---------------- dis + row allocation (wave scan) ----------------
__global__ __launch_bounds__(256) void alloc_kernel(const int* __restrict__ cnt,
                                                    float* __restrict__ dis, int* __restrict__ rowptr,
                                                    int* __restrict__ total) {
    int i = blockIdx.x * 256 + threadIdx.x;
    int c = (i < N_NODES) ? cnt[i] : 0;
    if (i < N_NODES) dis[i] = rsqrtf((float)(c + 1));
    int lane = threadIdx.x & 63;
    int s = c;
    #pragma unroll
    for (int o = 1; o < 64; o <<= 1) {
        int v = __shfl_up(s, o, 64);
        if (lane >= o) s += v;
    }
    int wtot = __shfl(s, 63, 64);
    int base = 0;
    if (lane == 0) base = atomicAdd(total, wtot);
    base = __shfl(base, 0, 64);
    if (i < N_NODES) rowptr[i] = base + s - c;   // exclusive within wave
}

// ---------------- CSR fill (no atomics: slot precomputed) ----------------
__global__ __launch_bounds__(256) void fill_kernel(const int* __restrict__ src, const int* __restrict__ dst,
                                                   const int* __restrict__ rowptr, const int* __restrict__ pos,
                                                   int* __restrict__ colb) {
    int e = blockIdx.x * 256 + threadIdx.x;
    if (e >= N_EDGES) return;
    colb[rowptr[dst[e]] + pos[e]] = src[e];
}

// ---------------- GEMM1: hs1 = dis * (x @ W1), [N,128]x[128,32] ----------------
__global__ __launch_bounds__(256) void gemm1_kernel(const float* __restrict__ x, const float* __restrict__ W1,
                                                    const float* __restrict__ dis, float* __restrict__ hs1) {
    __shared__ float xs[64][128];     // 32 KB
    __shared__ float wt[32][132];     // W1^T padded
    int tid = threadIdx.x;
    int r0 = blockIdx.x * 64;
    for (int idx = tid; idx < 128 * 32; idx += 256) {
        int k = idx >> 5, j = idx & 31;
        wt[j][k] = W1[idx];
    }
    for (int idx = tid; idx < 64 * 32; idx += 256) {
        int r = idx >> 5, kc = idx & 31;
        int gr = r0 + r;
        float4 v = (gr < N_NODES) ? ((const float4*)x)[(size_t)gr * 32 + kc] : make_float4(0.f, 0.f, 0.f, 0.f);
        *(float4*)&xs[r][kc * 4] = v;
    }
    __syncthreads();
    int j = tid & 31;
    int rr = tid >> 5;   // 0..7
    float acc[8];
    #pragma unroll
    for (int i = 0; i < 8; i++) acc[i] = 0.f;
    for (int kc = 0; kc < 128; kc += 4) {
        float4 wv = *(const float4*)&wt[j][kc];
        #pragma unroll
        for (int i = 0; i < 8; i++) {
            float4 xv = *(const float4*)&xs[rr + i * 8][kc];
            acc[i] += xv.x * wv.x + xv.y * wv.y + xv.z * wv.z + xv.w * wv.w;
        }
    }
    #pragma unroll
    for (int i = 0; i < 8; i++) {
        int gr = r0 + rr + i * 8;
        if (gr < N_NODES) hs1[(size_t)gr * 32 + j] = dis[gr] * acc[i];
    }
}

// ---------------- agg1 + gemm2 fused, lane-parallel edges:
//   one wave per row; lane = (es in [0,8), q in [0,8)); float4 gathers, 16 edges in flight
//   h1 = lrelu(dis*(sum_neigh hs1 + self) + b1) in LDS; hs2 = dis * (h1 @ W2)
__global__ __launch_bounds__(256) void agg1_kernel(const float* __restrict__ hs1, const int* __restrict__ colb,
                                                   const int* __restrict__ rowptr, const int* __restrict__ cnt,
                                                   const float* __restrict__ dis, const float* __restrict__ b1,
                                                   const float* __restrict__ W2, float* __restrict__ hs2) {
    __shared__ float h1s[4][32];
    __shared__ float w2s[32][64];
    int tid = threadIdx.x;
    for (int idx = tid; idx < 32 * 64; idx += 256) w2s[idx >> 6][idx & 63] = W2[idx];
    int wid = tid >> 6;
    int lane = tid & 63;
    int es = lane >> 3;   // edge slot 0..7
    int q = lane & 7;     // feature quad 0..7
    int r = blockIdx.x * 4 + wid;          // N_NODES % 4 == 0, grid exact
    int start = rowptr[r];
    int n = cnt[r];
    float4 acc0 = make_float4(0.f, 0.f, 0.f, 0.f);
    float4 acc1 = acc0;
    if (es == 0) acc0 = *(const float4*)&hs1[(size_t)r * 32 + q * 4];   // self
    for (int k = 0; k < n; k += 16) {
        int e0 = k + es, e1 = k + 8 + es;
        if (e0 < n) {
            int c = colb[start + e0];
            float4 v = *(const float4*)&hs1[(size_t)c * 32 + q * 4];
            acc0.x += v.x; acc0.y += v.y; acc0.z += v.z; acc0.w += v.w;
        }
        if (e1 < n) {
            int c = colb[start + e1];
            float4 v = *(const float4*)&hs1[(size_t)c * 32 + q * 4];
            acc1.x += v.x; acc1.y += v.y; acc1.z += v.z; acc1.w += v.w;
        }
    }
    float4 a;
    a.x = acc0.x + acc1.x; a.y = acc0.y + acc1.y; a.z = acc0.z + acc1.z; a.w = acc0.w + acc1.w;
    #pragma unroll
    for (int m = 8; m < 64; m <<= 1) {
        a.x += __shfl_xor(a.x, m, 64);
        a.y += __shfl_xor(a.y, m, 64);
        a.z += __shfl_xor(a.z, m, 64);
        a.w += __shfl_xor(a.w, m, 64);
    }
    if (es == 0) {
        float4 bv = *(const float4*)&b1[q * 4];
        float dr = dis[r];
        float4 v;
        v.x = dr * a.x + bv.x; v.y = dr * a.y + bv.y; v.z = dr * a.z + bv.z; v.w = dr * a.w + bv.w;
        v.x = v.x > 0.f ? v.x : 0.1f * v.x;
        v.y = v.y > 0.f ? v.y : 0.1f * v.y;
        v.z = v.z > 0.f ? v.z : 0.1f * v.z;
        v.w = v.w > 0.f ? v.w : 0.1f * v.w;
        *(float4*)&h1s[wid][q * 4] = v;
    }
    __syncthreads();
    // phase 2: each wave computes hs2 row for its own r; j across 64 lanes
    int j = lane;
    float s = 0.f;
    #pragma unroll
    for (int k2 = 0; k2 < 32; k2++) s += h1s[wid][k2] * w2s[k2][j];
    hs2[(size_t)r * 64 + j] = dis[r] * s;
}

// ---------------- agg2 + global-max-pool fused, lane-parallel edges:
//   one wave per row; lane = (es in [0,4), q in [0,16)); 8 edges in flight
//   row value -> per-block LDS max -> ordered-uint atomicMax into gbufu
__global__ __launch_bounds__(256) void agg2_kernel(const float* __restrict__ hs2, const int* __restrict__ colb,
                                                   const int* __restrict__ rowptr, const int* __restrict__ cnt,
                                                   const float* __restrict__ dis, const float* __restrict__ b2,
                                                   const int* __restrict__ batch, unsigned* __restrict__ gbufu) {
    __shared__ float red[4][64];
    __shared__ int rg[4];
    int tid = threadIdx.x;
    int wid = tid >> 6;
    int lane = tid & 63;
    int es = lane >> 4;   // edge slot 0..3
    int q = lane & 15;    // feature quad 0..15
    int r = blockIdx.x * 4 + wid;
    int start = rowptr[r];
    int n = cnt[r];
    float4 acc0 = make_float4(0.f, 0.f, 0.f, 0.f);
    float4 acc1 = acc0;
    if (es == 0) acc0 = *(const float4*)&hs2[(size_t)r * 64 + q * 4];   // self
    for (int k = 0; k < n; k += 8) {
        int e0 = k + es, e1 = k + 4 + es;
        if (e0 < n) {
            int c = colb[start + e0];
            float4 v = *(const float4*)&hs2[(size_t)c * 64 + q * 4];
            acc0.x += v.x; acc0.y += v.y; acc0.z += v.z; acc0.w += v.w;
        }
        if (e1 < n) {
            int c = colb[start + e1];
            float4 v = *(const float4*)&hs2[(size_t)c * 64 + q * 4];
            acc1.x += v.x; acc1.y += v.y; acc1.z += v.z; acc1.w += v.w;
        }
    }
    float4 a;
    a.x = acc0.x + acc1.x; a.y = acc0.y + acc1.y; a.z = acc0.z + acc1.z; a.w = acc0.w + acc1.w;
    #pragma unroll
    for (int m = 16; m < 64; m <<= 1) {
        a.x += __shfl_xor(a.x, m, 64);
        a.y += __shfl_xor(a.y, m, 64);
        a.z += __shfl_xor(a.z, m, 64);
        a.w += __shfl_xor(a.w, m, 64);
    }
    if (es == 0) {
        float4 bv = *(const float4*)&b2[q * 4];
        float dr = dis[r];
        float4 v;
        v.x = dr * a.x + bv.x; v.y = dr * a.y + bv.y; v.z = dr * a.z + bv.z; v.w = dr * a.w + bv.w;
        *(float4*)&red[wid][q * 4] = v;
    }
    if (lane == 0) rg[wid] = batch[r];
    __syncthreads();
    if (tid < 64) {
        int g0 = rg[0];
        bool uni = (rg[1] == g0) & (rg[2] == g0) & (rg[3] == g0);
        if (uni) {
            float m = fmaxf(fmaxf(red[0][tid], red[1][tid]), fmaxf(red[2][tid], red[3][tid]));
            atomicMax(&gbufu[g0 * 64 + tid], f2o(m));
        } else {
            #pragma unroll
            for (int w = 0; w < 4; w++) atomicMax(&gbufu[rg[w] * 64 + tid], f2o(red[w][tid]));
        }
    }
}

// ---------------- MLP head, single block ----------------
__global__ __launch_bounds__(256) void mlp_kernel(const unsigned* __restrict__ gbufu,
                                                  const float* __restrict__ Wl1, const float* __restrict__ bl1,
                                                  const float* __restrict__ Wl2, const float* __restrict__ bl2,
                                                  const float* __restrict__ Wl3, const float* __restrict__ bl3,
                                                  float* __restrict__ out) {
    __shared__ float A[64][64];
    __shared__ float B[64][128];
    int tid = threadIdx.x;
    for (int idx = tid; idx < 64 * 64; idx += 256) A[idx >> 6][idx & 63] = o2f(gbufu[idx]);
    __syncthreads();
    {
        int j = tid & 127;
        int rg = tid >> 7;
        float wc[64];
        #pragma unroll
        for (int k = 0; k < 64; k++) wc[k] = Wl1[k * 128 + j];
        float bj = bl1[j];
        for (int r = rg; r < 64; r += 2) {
            float acc = bj;
            #pragma unroll
            for (int kc = 0; kc < 64; kc += 4) {
                float4 av = *(const float4*)&A[r][kc];
                acc += av.x * wc[kc] + av.y * wc[kc + 1] + av.z * wc[kc + 2] + av.w * wc[kc + 3];
            }
            B[r][j] = acc > 0.f ? acc : 0.1f * acc;
        }
    }
    __syncthreads();
    {
        int j = tid & 63;
        int rg = tid >> 6;
        float wc[128];
        #pragma unroll
        for (int k = 0; k < 128; k++) wc[k] = Wl2[k * 64 + j];
        float bj = bl2[j];
        for (int r = rg; r < 64; r += 4) {
            float acc = bj;
            #pragma unroll
            for (int kc = 0; kc < 128; kc += 4) {
                float4 bv = *(const float4*)&B[r][kc];
                acc += bv.x * wc[kc] + bv.y * wc[kc + 1] + bv.z * wc[kc + 2] + bv.w * wc[kc + 3];
            }
            A[r][j] = acc > 0.f ? acc : 0.1f * acc;
        }
    }
    __syncthreads();
    if (tid < 64) {
        int r = tid;
        float acc = bl3[0];
        #pragma unroll
        for (int k = 0; k < 64; k++) acc += A[r][k] * Wl3[k];
        out[r] = acc;
    }
}

extern "C" void kernel_launch(void* const* d_in, const int* in_sizes, int n_in,
                              void* d_out, int out_size, void* d_ws, size_t ws_size,
                              hipStream_t stream) {
    (void)in_sizes; (void)n_in; (void)out_size; (void)ws_size;
    const float* x    = (const float*)d_in[0];
    const int*   edge = (const int*)d_in[1];
    const int*   batch= (const int*)d_in[2];
    const float* W1   = (const float*)d_in[3];
    const float* b1   = (const float*)d_in[4];
    const float* W2   = (const float*)d_in[5];
    const float* b2   = (const float*)d_in[6];
    const float* Wl1  = (const float*)d_in[7];
    const float* bl1  = (const float*)d_in[8];
    const float* Wl2  = (const float*)d_in[9];
    const float* bl2  = (const float*)d_in[10];
    const float* Wl3  = (const float*)d_in[11];
    const float* bl3  = (const float*)d_in[12];
    const int* srcp = edge;
    const int* dstp = edge + N_EDGES;

    // workspace layout: zeroed region first = cnt[N] + total[1] + gbufu[64*64] -> one memset
    char* ws = (char*)d_ws;
    int*      cnt   = (int*)ws;
    int*      total = cnt + N_NODES;
    unsigned* gbufu = (unsigned*)(total + 1);
    size_t zeroed = (size_t)(N_NODES + 1 + N_GRAPHS * 64) * 4;
    size_t off = (zeroed + 255) & ~(size_t)255;
    auto alloc = [&](size_t bytes) { char* p = ws + off; off = (off + bytes + 255) & ~(size_t)255; return p; };
    int*   pos    = (int*)alloc((size_t)N_EDGES * 4);
    int*   rowptr = (int*)alloc((size_t)N_NODES * 4);
    float* dis    = (float*)alloc((size_t)N_NODES * 4);
    int*   colb   = (int*)alloc((size_t)N_EDGES * 4);
    float* hs1    = (float*)alloc((size_t)N_NODES * 32 * 4);
    float* hs2    = (float*)alloc((size_t)N_NODES * 64 * 4);

    hipMemsetAsync(ws, 0, zeroed, stream);

    deg_kernel  <<<(N_EDGES + 255) / 256, 256, 0, stream>>>(dstp, cnt, pos);
    alloc_kernel<<<(N_NODES + 255) / 256, 256, 0, stream>>>(cnt, dis, rowptr, total);
    fill_kernel <<<(N_EDGES + 255) / 256, 256, 0, stream>>>(srcp, dstp, rowptr, pos, colb);
    gemm1_kernel<<<(N_NODES + 63) / 64, 256, 0, stream>>>(x, W1, dis, hs1);
    agg1_kernel <<<N_NODES / 4, 256, 0, stream>>>(hs1, colb, rowptr, cnt, dis, b1, W2, hs2);
    agg2_kernel <<<N_NODES / 4, 256, 0, stream>>>(hs2, colb, rowptr, cnt, dis, b2, batch, gbufu);
    mlp_kernel  <<<1, 256, 0, stream>>>(gbufu, Wl1, bl1, Wl2, bl2, Wl3, bl3, (float*)d_out);
}